// Round 3
// baseline (672.143 us; speedup 1.0000x reference)
//
#include <hip/hip_runtime.h>
#include <stdint.h>

typedef __attribute__((ext_vector_type(8))) __bf16 v8bf;
typedef __attribute__((ext_vector_type(4))) __bf16 v4bf;
typedef __attribute__((ext_vector_type(4))) float  v4f;

#define SCALE 0.125f

__device__ __forceinline__ unsigned short f2bf(float f) {
  unsigned u = __float_as_uint(f);
  u += 0x7fffu + ((u >> 16) & 1u);   // RNE
  return (unsigned short)(u >> 16);
}

// ---------------------------------------------------------------------------
// Weight transpose+cast: in fp32 [K][N] row-major -> out bf16 [N][K]
// ---------------------------------------------------------------------------
__global__ void __launch_bounds__(256) k_transpose_cast(
    const float* __restrict__ in, unsigned short* __restrict__ out, int K, int N) {
  __shared__ float tile[64][65];
  const int t  = threadIdx.x;
  const int kt = blockIdx.x * 64;
  const int nt = blockIdx.y * 64;
  {
    int kl = t >> 2;
    int c0 = (t & 3) * 16;
    const float* src = in + (size_t)(kt + kl) * N + nt + c0;
#pragma unroll
    for (int i = 0; i < 16; i += 4) {
      float4 v = *(const float4*)(src + i);
      tile[kl][c0 + i + 0] = v.x; tile[kl][c0 + i + 1] = v.y;
      tile[kl][c0 + i + 2] = v.z; tile[kl][c0 + i + 3] = v.w;
    }
  }
  __syncthreads();
  {
    int nl = t >> 2;
    int k0 = (t & 3) * 16;
    unsigned short* dst = out + (size_t)(nt + nl) * K + kt + k0;
#pragma unroll
    for (int i = 0; i < 16; ++i) dst[i] = f2bf(tile[k0 + i][nl]);
  }
}

// ---------------------------------------------------------------------------
// Gather rows into window order + cast fp32 -> bf16.
// ---------------------------------------------------------------------------
__global__ void __launch_bounds__(256) k_gather_cast(
    const float* __restrict__ x, unsigned short* __restrict__ xg) {
  const int t  = threadIdx.x;
  const int m  = blockIdx.x * 4 + (t >> 6);
  const int i0 = (t & 63) * 8;
  const int b = m >> 12, r = m & 4095, win = r >> 6, tt = r & 63;
  const int y  = ((win >> 3) << 3) + (tt >> 3);
  const int xx = ((win & 7) << 3) + (tt & 7);
  const size_t s = ((size_t)b << 12) + (size_t)y * 64 + xx;
  const float4* src = (const float4*)(x + s * 512 + i0);
  float4 a = src[0], c = src[1];
  unsigned u0 = (unsigned)f2bf(a.x) | ((unsigned)f2bf(a.y) << 16);
  unsigned u1 = (unsigned)f2bf(a.z) | ((unsigned)f2bf(a.w) << 16);
  unsigned u2 = (unsigned)f2bf(c.x) | ((unsigned)f2bf(c.y) << 16);
  unsigned u3 = (unsigned)f2bf(c.z) | ((unsigned)f2bf(c.w) << 16);
  *(int4*)(xg + (size_t)m * 512 + i0) = make_int4((int)u0, (int)u1, (int)u2, (int)u3);
}

// ---------------------------------------------------------------------------
// Barrier-free GEMM core (K=512, small-K / L2-resident-B specialization):
// no LDS at all. Wave = 64 rows x 128 cols (4x8 frags of 16x16x32).
// A,B fragments are 16B-contiguous global segments -> direct VGPR loads,
// L1/L2-served. Block = 4 waves stacked in M (256 rows x 128 cols).
// ---------------------------------------------------------------------------
__device__ __forceinline__ void gemm_core(const unsigned short* __restrict__ A,
                                          const unsigned short* __restrict__ Bt,
                                          int wRow, int colBase, v4f (&acc)[4][8]) {
  const int lane = threadIdx.x & 63;
  const int la = lane & 15, lb = lane >> 4;
  const unsigned short* ap = A  + (size_t)(wRow    + la) * 512 + lb * 8;
  const unsigned short* bp = Bt + (size_t)(colBase + la) * 512 + lb * 8;
#pragma unroll 2
  for (int kk = 0; kk < 16; ++kk) {
    v8bf a[4], b[8];
#pragma unroll
    for (int m = 0; m < 4; ++m)
      a[m] = *(const v8bf*)(ap + kk * 32 + (size_t)m * 16 * 512);
#pragma unroll
    for (int n = 0; n < 8; ++n)
      b[n] = *(const v8bf*)(bp + kk * 32 + (size_t)n * 16 * 512);
#pragma unroll
    for (int m = 0; m < 4; ++m)
#pragma unroll
      for (int n = 0; n < 8; ++n)
        acc[m][n] = __builtin_amdgcn_mfma_f32_16x16x32_bf16(a[m], b[n], acc[m][n], 0, 0, 0);
  }
}

// GEMM1: QKV = Xg @ WqkvT + b -> bf16 [65536][1536]
// grid 3072 = 256 row-tiles x 12 col-panels; XCD-grouped so each XCD sweeps
// all 12 panels per row-tile (A-tile L2-hot across panels, B always L2-hot).
__global__ void __launch_bounds__(256, 2) k_gemm_qkv(
    const unsigned short* __restrict__ A, const unsigned short* __restrict__ Bt,
    const float* __restrict__ bias, unsigned short* __restrict__ C) {
  const int bid = blockIdx.x;
  const int x = bid & 7, j = bid >> 3;        // j in 0..383
  const int tm = x * 32 + j / 12, tn = j % 12;
  const int wid = threadIdx.x >> 6;
  const int wRow = tm * 256 + wid * 64;
  const int colBase = tn * 128;
  v4f acc[4][8] = {};
  gemm_core(A, Bt, wRow, colBase, acc);
  const int lane = threadIdx.x & 63, la = lane & 15, lb = lane >> 4;
  float bv[8];
#pragma unroll
  for (int n = 0; n < 8; ++n) bv[n] = bias[colBase + n * 16 + la];
#pragma unroll
  for (int m = 0; m < 4; ++m)
#pragma unroll
    for (int jj = 0; jj < 4; ++jj) {
      const size_t row = (size_t)wRow + m * 16 + lb * 4 + jj;
      unsigned short* crow = C + row * 1536 + colBase + la;
#pragma unroll
      for (int n = 0; n < 8; ++n)
        crow[n * 16] = f2bf(acc[m][n][jj] + bv[n]);
    }
}

// GEMM3: out = O @ WprojT + b, fp32 output scattered back to raster order.
__global__ void __launch_bounds__(256, 2) k_gemm_proj(
    const unsigned short* __restrict__ A, const unsigned short* __restrict__ Bt,
    const float* __restrict__ bias, float* __restrict__ out) {
  const int bid = blockIdx.x;                 // 1024
  const int x = bid & 7, j = bid >> 3;        // j in 0..127
  const int tm = x * 32 + j / 4, tn = j & 3;
  const int wid = threadIdx.x >> 6;
  const int wRow = tm * 256 + wid * 64;
  const int colBase = tn * 128;
  v4f acc[4][8] = {};
  gemm_core(A, Bt, wRow, colBase, acc);
  const int lane = threadIdx.x & 63, la = lane & 15, lb = lane >> 4;
  float bv[8];
#pragma unroll
  for (int n = 0; n < 8; ++n) bv[n] = bias[colBase + n * 16 + la];
#pragma unroll
  for (int m = 0; m < 4; ++m)
#pragma unroll
    for (int jj = 0; jj < 4; ++jj) {
      const int row = wRow + m * 16 + lb * 4 + jj;   // window-ordered
      const int b = row >> 12, r = row & 4095, win = r >> 6, tt = r & 63;
      const int y  = ((win >> 3) << 3) + (tt >> 3);
      const int xx = ((win & 7) << 3) + (tt & 7);
      const size_t srow = ((size_t)b << 12) + (size_t)y * 64 + xx;
      float* orow = out + srow * 512 + colBase + la;
#pragma unroll
      for (int n = 0; n < 8; ++n)
        orow[n * 16] = acc[m][n][jj] + bv[n];
    }
}

// ---------------------------------------------------------------------------
// Windowed attention: one block per (b, win, head). 4 waves x 16 rows.
// (unchanged from round 2 — counters next round will rank it)
// ---------------------------------------------------------------------------
__global__ void __launch_bounds__(256) k_attn(
    const unsigned short* __restrict__ QKV, unsigned short* __restrict__ O) {
  __shared__ unsigned short sQ[64 * 72];
  __shared__ unsigned short sK[64 * 72];
  __shared__ unsigned short sP[64 * 72];
  __shared__ unsigned short sVt[64 * 68];
  const int bid = blockIdx.x;                      // 8192
  const int b = bid >> 9, win = (bid >> 3) & 63, head = bid & 7;
  const size_t m0 = ((size_t)b << 12) + (size_t)win * 64;
  const int tid = threadIdx.x, lane = tid & 63, w = tid >> 6;
  const int la = lane & 15, lb = lane >> 4;

  {
    const int rowl = tid >> 2;
    const unsigned short* qrow = QKV + (m0 + rowl) * 1536;
#pragma unroll
    for (int p = 0; p < 2; ++p) {
      const int seg = (tid & 3) + p * 4;
      int4 vq = *(const int4*)(qrow + head * 64 + seg * 8);
      *(int4*)&sQ[rowl * 72 + seg * 8] = vq;
      int4 vk = *(const int4*)(qrow + 512 + head * 64 + seg * 8);
      *(int4*)&sK[rowl * 72 + seg * 8] = vk;
      int4 vv = *(const int4*)(qrow + 1024 + head * 64 + seg * 8);
      const unsigned short* pv = (const unsigned short*)&vv;
#pragma unroll
      for (int i = 0; i < 8; ++i)
        sVt[(seg * 8 + i) * 68 + rowl] = pv[i];
    }
  }
  __syncthreads();

  v4f sc[4] = {};
#pragma unroll
  for (int kk = 0; kk < 2; ++kk) {
    v8bf aq = *(const v8bf*)&sQ[(w * 16 + la) * 72 + kk * 32 + lb * 8];
#pragma unroll
    for (int n = 0; n < 4; ++n) {
      v8bf bk = *(const v8bf*)&sK[(n * 16 + la) * 72 + kk * 32 + lb * 8];
      sc[n] = __builtin_amdgcn_mfma_f32_16x16x32_bf16(aq, bk, sc[n], 0, 0, 0);
    }
  }
#pragma unroll
  for (int n = 0; n < 4; ++n) sc[n] *= SCALE;

  float mj[4], sj[4], pv_[4][4];
#pragma unroll
  for (int j = 0; j < 4; ++j) {
    float mx = fmaxf(fmaxf(sc[0][j], sc[1][j]), fmaxf(sc[2][j], sc[3][j]));
    mx = fmaxf(mx, __shfl_xor(mx, 1));
    mx = fmaxf(mx, __shfl_xor(mx, 2));
    mx = fmaxf(mx, __shfl_xor(mx, 4));
    mx = fmaxf(mx, __shfl_xor(mx, 8));
    mj[j] = mx;
  }
#pragma unroll
  for (int j = 0; j < 4; ++j) {
    float sum = 0.f;
#pragma unroll
    for (int n = 0; n < 4; ++n) { pv_[n][j] = __expf(sc[n][j] - mj[j]); sum += pv_[n][j]; }
    sum += __shfl_xor(sum, 1);
    sum += __shfl_xor(sum, 2);
    sum += __shfl_xor(sum, 4);
    sum += __shfl_xor(sum, 8);
    sj[j] = sum;
  }
#pragma unroll
  for (int n = 0; n < 4; ++n)
#pragma unroll
    for (int j = 0; j < 4; ++j)
      sP[(w * 16 + lb * 4 + j) * 72 + n * 16 + la] = f2bf(pv_[n][j]);

  v4f oa[4] = {};
#pragma unroll
  for (int kk = 0; kk < 2; ++kk) {
    v8bf ap = *(const v8bf*)&sP[(w * 16 + la) * 72 + kk * 32 + lb * 8];
#pragma unroll
    for (int n = 0; n < 4; ++n) {
      const int vidx = (n * 16 + la) * 68 + kk * 32 + lb * 8;
      v4bf lo = *(const v4bf*)&sVt[vidx];
      v4bf hi = *(const v4bf*)&sVt[vidx + 4];
      v8bf bv;
#pragma unroll
      for (int i = 0; i < 4; ++i) { bv[i] = lo[i]; bv[i + 4] = hi[i]; }
      oa[n] = __builtin_amdgcn_mfma_f32_16x16x32_bf16(ap, bv, oa[n], 0, 0, 0);
    }
  }
#pragma unroll
  for (int j = 0; j < 4; ++j) {
    const float inv = 1.0f / sj[j];
#pragma unroll
    for (int n = 0; n < 4; ++n)
      O[(m0 + w * 16 + lb * 4 + j) * 512 + head * 64 + n * 16 + la] = f2bf(oa[n][j] * inv);
  }
}

// ---------------------------------------------------------------------------
extern "C" void kernel_launch(void* const* d_in, const int* in_sizes, int n_in,
                              void* d_out, int out_size, void* d_ws, size_t ws_size,
                              hipStream_t stream) {
  const float* hidden = (const float*)d_in[1];
  const float* qkv_w  = (const float*)d_in[2];
  const float* qkv_b  = (const float*)d_in[3];
  const float* proj_w = (const float*)d_in[4];
  const float* proj_b = (const float*)d_in[5];
  float* out = (float*)d_out;

  char* ws = (char*)d_ws;
  unsigned short* QKV = (unsigned short*)(ws);                    // 201,326,592 B
  unsigned short* Xg  = (unsigned short*)(ws + 201326592);        //  67,108,864 B (reused as O)
  unsigned short* Wq  = (unsigned short*)(ws + 268435456);        //   1,572,864 B
  unsigned short* Wp  = (unsigned short*)(ws + 270008320);        //     524,288 B
  if (ws_size < 270532608) return;  // workspace too small: fail loudly
  unsigned short* Obuf = Xg;        // Xg dead after GEMM1 -> alias

  k_transpose_cast<<<dim3(8, 24), 256, 0, stream>>>(qkv_w, Wq, 512, 1536);
  k_transpose_cast<<<dim3(8, 8),  256, 0, stream>>>(proj_w, Wp, 512, 512);
  k_gather_cast<<<16384, 256, 0, stream>>>(hidden, Xg);
  k_gemm_qkv<<<3072, 256, 0, stream>>>(Xg, Wq, qkv_b, QKV);
  k_attn<<<8192, 256, 0, stream>>>(QKV, Obuf);
  k_gemm_proj<<<1024, 256, 0, stream>>>(Obuf, Wp, proj_b, out);
}

// Round 5
// 489.033 us; speedup vs baseline: 1.3744x; 1.3744x over previous
//
#include <hip/hip_runtime.h>
#include <stdint.h>

typedef __attribute__((ext_vector_type(8))) __bf16 v8bf;
typedef __attribute__((ext_vector_type(4))) __bf16 v4bf;
typedef __attribute__((ext_vector_type(4))) float  v4f;

#define SCALE 0.125f

__device__ __forceinline__ unsigned short f2bf(float f) {
  unsigned u = __float_as_uint(f);
  u += 0x7fffu + ((u >> 16) & 1u);   // RNE
  return (unsigned short)(u >> 16);
}

// ---------------------------------------------------------------------------
// Weight transpose+cast: in fp32 [K][N] row-major -> out bf16 [N][K]
// ---------------------------------------------------------------------------
__global__ void __launch_bounds__(256) k_transpose_cast(
    const float* __restrict__ in, unsigned short* __restrict__ out, int K, int N) {
  __shared__ float tile[64][65];
  const int t  = threadIdx.x;
  const int kt = blockIdx.x * 64;
  const int nt = blockIdx.y * 64;
  {
    int kl = t >> 2;
    int c0 = (t & 3) * 16;
    const float* src = in + (size_t)(kt + kl) * N + nt + c0;
#pragma unroll
    for (int i = 0; i < 16; i += 4) {
      float4 v = *(const float4*)(src + i);
      tile[kl][c0 + i + 0] = v.x; tile[kl][c0 + i + 1] = v.y;
      tile[kl][c0 + i + 2] = v.z; tile[kl][c0 + i + 3] = v.w;
    }
  }
  __syncthreads();
  {
    int nl = t >> 2;
    int k0 = (t & 3) * 16;
    unsigned short* dst = out + (size_t)(nt + nl) * K + kt + k0;
#pragma unroll
    for (int i = 0; i < 16; ++i) dst[i] = f2bf(tile[k0 + i][nl]);
  }
}

// ---------------------------------------------------------------------------
// Gather rows into window order + cast fp32 -> bf16.
// ---------------------------------------------------------------------------
__global__ void __launch_bounds__(256) k_gather_cast(
    const float* __restrict__ x, unsigned short* __restrict__ xg) {
  const int t  = threadIdx.x;
  const int m  = blockIdx.x * 4 + (t >> 6);
  const int i0 = (t & 63) * 8;
  const int b = m >> 12, r = m & 4095, win = r >> 6, tt = r & 63;
  const int y  = ((win >> 3) << 3) + (tt >> 3);
  const int xx = ((win & 7) << 3) + (tt & 7);
  const size_t s = ((size_t)b << 12) + (size_t)y * 64 + xx;
  const float4* src = (const float4*)(x + s * 512 + i0);
  float4 a = src[0], c = src[1];
  unsigned u0 = (unsigned)f2bf(a.x) | ((unsigned)f2bf(a.y) << 16);
  unsigned u1 = (unsigned)f2bf(a.z) | ((unsigned)f2bf(a.w) << 16);
  unsigned u2 = (unsigned)f2bf(c.x) | ((unsigned)f2bf(c.y) << 16);
  unsigned u3 = (unsigned)f2bf(c.z) | ((unsigned)f2bf(c.w) << 16);
  *(int4*)(xg + (size_t)m * 512 + i0) = make_int4((int)u0, (int)u1, (int)u2, (int)u3);
}

// ---------------------------------------------------------------------------
// 2-phase double-buffered m97-style GEMM core: 128x128 tile, BK=32, 4 waves.
// Per K-step: issue next-step global_load_lds FIRST, then ds_read+MFMA on
// current buffer, then ONE __syncthreads (compiler's pre-barrier vmcnt drain
// overlaps the MFMA phase instead of stalling cold).
// ---------------------------------------------------------------------------
__device__ __forceinline__ void stage_tile(const unsigned short* g, int row0, int k0,
                                           unsigned short* s, int tid) {
#pragma unroll
  for (int p = 0; p < 2; ++p) {
    int o = p * 4096 + tid * 16;  // byte offset within 8KB tile (rows of 64B)
    const char* src = (const char*)g + (((size_t)(row0 + (o >> 6))) << 10) + (k0 << 1) + (o & 63);
    char* dst = (char*)s + p * 4096 + (tid & ~63) * 16;  // wave-uniform base
    __builtin_amdgcn_global_load_lds((const __attribute__((address_space(1))) void*)src,
                                     (__attribute__((address_space(3))) void*)dst, 16, 0, 0);
  }
}

__device__ __forceinline__ void gemm_core(const unsigned short* A, const unsigned short* Bt,
                                          int rowBase, int colBase,
                                          unsigned short (&sA)[2][4096],
                                          unsigned short (&sB)[2][4096],
                                          v4f (&acc)[4][4]) {
  const int tid = threadIdx.x;
  const int lane = tid & 63, wid = tid >> 6;
  const int wr = wid >> 1, wc = wid & 1;
  const int la = lane & 15, lb = lane >> 4;

  stage_tile(A,  rowBase, 0, sA[0], tid);
  stage_tile(Bt, colBase, 0, sB[0], tid);
  __syncthreads();

  int cur = 0;
#pragma unroll 1
  for (int kt = 0; kt < 16; ++kt) {
    if (kt < 15) {  // prefetch next K-step into the other buffer
      const int k1 = (kt + 1) * 32;
      stage_tile(A,  rowBase, k1, sA[cur ^ 1], tid);
      stage_tile(Bt, colBase, k1, sB[cur ^ 1], tid);
    }
    v8bf af[4], bf_[4];
#pragma unroll
    for (int m = 0; m < 4; ++m)
      af[m] = *(const v8bf*)&sA[cur][(wr * 64 + m * 16 + la) * 32 + lb * 8];
#pragma unroll
    for (int n = 0; n < 4; ++n)
      bf_[n] = *(const v8bf*)&sB[cur][(wc * 64 + n * 16 + la) * 32 + lb * 8];
#pragma unroll
    for (int m = 0; m < 4; ++m)
#pragma unroll
      for (int n = 0; n < 4; ++n)
        acc[m][n] = __builtin_amdgcn_mfma_f32_16x16x32_bf16(af[m], bf_[n], acc[m][n], 0, 0, 0);
    __syncthreads();   // drains vmcnt (next-tile loads) + lgkm; one barrier per step
    cur ^= 1;
  }
}

// GEMM1: QKV = Xg @ WqkvT + b -> bf16 [65536][1536]
__global__ void __launch_bounds__(256) k_gemm_qkv(
    const unsigned short* __restrict__ A, const unsigned short* __restrict__ Bt,
    const float* __restrict__ bias, unsigned short* __restrict__ C) {
  __shared__ unsigned short sA[2][4096];
  __shared__ unsigned short sB[2][4096];
  const int bid = blockIdx.x;                    // 6144 = 512 x 12
  const int b2 = (bid & 7) * 768 + (bid >> 3);   // bijective XCD swizzle
  const int tm = b2 / 12, tn = b2 % 12;
  const int rowBase = tm * 128, colBase = tn * 128;
  v4f acc[4][4] = {};
  gemm_core(A, Bt, rowBase, colBase, sA, sB, acc);
  const int tid = threadIdx.x, lane = tid & 63, wid = tid >> 6;
  const int wr = wid >> 1, wc = wid & 1, la = lane & 15, lb = lane >> 4;
#pragma unroll
  for (int n = 0; n < 4; ++n) {
    const int col = colBase + wc * 64 + n * 16 + la;
    const float bv = bias[col];
#pragma unroll
    for (int m = 0; m < 4; ++m)
#pragma unroll
      for (int j = 0; j < 4; ++j) {
        const size_t row = (size_t)rowBase + wr * 64 + m * 16 + lb * 4 + j;
        C[row * 1536 + col] = f2bf(acc[m][n][j] + bv);
      }
  }
}

// GEMM3: out = O @ WprojT + b, fp32 output scattered back to raster order
__global__ void __launch_bounds__(256) k_gemm_proj(
    const unsigned short* __restrict__ A, const unsigned short* __restrict__ Bt,
    const float* __restrict__ bias, float* __restrict__ out) {
  __shared__ unsigned short sA[2][4096];
  __shared__ unsigned short sB[2][4096];
  const int bid = blockIdx.x;                    // 2048 = 512 x 4
  const int b2 = (bid & 7) * 256 + (bid >> 3);
  const int tm = b2 >> 2, tn = b2 & 3;
  const int rowBase = tm * 128, colBase = tn * 128;
  v4f acc[4][4] = {};
  gemm_core(A, Bt, rowBase, colBase, sA, sB, acc);
  const int tid = threadIdx.x, lane = tid & 63, wid = tid >> 6;
  const int wr = wid >> 1, wc = wid & 1, la = lane & 15, lb = lane >> 4;
#pragma unroll
  for (int m = 0; m < 4; ++m) {
#pragma unroll
    for (int j = 0; j < 4; ++j) {
      const int row = rowBase + wr * 64 + m * 16 + lb * 4 + j;  // window-ordered
      const int b = row >> 12, r = row & 4095, win = r >> 6, tt = r & 63;
      const int y  = ((win >> 3) << 3) + (tt >> 3);
      const int xx = ((win & 7) << 3) + (tt & 7);
      const size_t srow = ((size_t)b << 12) + (size_t)y * 64 + xx;
      float* orow = out + srow * 512;
#pragma unroll
      for (int n = 0; n < 4; ++n) {
        const int col = colBase + wc * 64 + n * 16 + la;
        orow[col] = acc[m][n][j] + bias[col];
      }
    }
  }
}

// ---------------------------------------------------------------------------
// Windowed attention: one block per (b, win, head). 4 waves x 16 rows.
// sP overlays sQ (each wave writes only its own 16 rows, which only it reads
// after QK^T) -> LDS 27.1 KB -> 5 blocks/CU instead of 4.
// ---------------------------------------------------------------------------
__global__ void __launch_bounds__(256) k_attn(
    const unsigned short* __restrict__ QKV, unsigned short* __restrict__ O) {
  __shared__ unsigned short sQ[64 * 72];   // later overlaid by P
  __shared__ unsigned short sK[64 * 72];
  __shared__ unsigned short sVt[64 * 68];
  unsigned short* sP = sQ;                 // safe overlay (per-wave-private rows)
  const int bid = blockIdx.x;                      // 8192
  const int b = bid >> 9, win = (bid >> 3) & 63, head = bid & 7;
  const size_t m0 = ((size_t)b << 12) + (size_t)win * 64;
  const int tid = threadIdx.x, lane = tid & 63, w = tid >> 6;
  const int la = lane & 15, lb = lane >> 4;

  {  // stage Q, K (linear padded rows) and V (transposed)
    const int rowl = tid >> 2;
    const unsigned short* qrow = QKV + (m0 + rowl) * 1536;
#pragma unroll
    for (int p = 0; p < 2; ++p) {
      const int seg = (tid & 3) + p * 4;
      int4 vq = *(const int4*)(qrow + head * 64 + seg * 8);
      *(int4*)&sQ[rowl * 72 + seg * 8] = vq;
      int4 vk = *(const int4*)(qrow + 512 + head * 64 + seg * 8);
      *(int4*)&sK[rowl * 72 + seg * 8] = vk;
      int4 vv = *(const int4*)(qrow + 1024 + head * 64 + seg * 8);
      const unsigned short* pv = (const unsigned short*)&vv;
#pragma unroll
      for (int i = 0; i < 8; ++i)
        sVt[(seg * 8 + i) * 68 + rowl] = pv[i];
    }
  }
  __syncthreads();

  // S = Q K^T  (wave w owns rows [w*16, w*16+16))
  v4f sc[4] = {};
#pragma unroll
  for (int kk = 0; kk < 2; ++kk) {
    v8bf aq = *(const v8bf*)&sQ[(w * 16 + la) * 72 + kk * 32 + lb * 8];
#pragma unroll
    for (int n = 0; n < 4; ++n) {
      v8bf bk = *(const v8bf*)&sK[(n * 16 + la) * 72 + kk * 32 + lb * 8];
      sc[n] = __builtin_amdgcn_mfma_f32_16x16x32_bf16(aq, bk, sc[n], 0, 0, 0);
    }
  }
#pragma unroll
  for (int n = 0; n < 4; ++n) sc[n] *= SCALE;

  // softmax over 64 cols: lane holds col n*16+la, rows lb*4+j
  float mj[4], sj[4], pv_[4][4];
#pragma unroll
  for (int j = 0; j < 4; ++j) {
    float mx = fmaxf(fmaxf(sc[0][j], sc[1][j]), fmaxf(sc[2][j], sc[3][j]));
    mx = fmaxf(mx, __shfl_xor(mx, 1));
    mx = fmaxf(mx, __shfl_xor(mx, 2));
    mx = fmaxf(mx, __shfl_xor(mx, 4));
    mx = fmaxf(mx, __shfl_xor(mx, 8));
    mj[j] = mx;
  }
#pragma unroll
  for (int j = 0; j < 4; ++j) {
    float sum = 0.f;
#pragma unroll
    for (int n = 0; n < 4; ++n) { pv_[n][j] = __expf(sc[n][j] - mj[j]); sum += pv_[n][j]; }
    sum += __shfl_xor(sum, 1);
    sum += __shfl_xor(sum, 2);
    sum += __shfl_xor(sum, 4);
    sum += __shfl_xor(sum, 8);
    sj[j] = sum;
  }
  // P -> LDS (bf16) over sQ; same wave re-reads its own 16 rows (no barrier)
#pragma unroll
  for (int n = 0; n < 4; ++n)
#pragma unroll
    for (int j = 0; j < 4; ++j)
      sP[(w * 16 + lb * 4 + j) * 72 + n * 16 + la] = f2bf(pv_[n][j]);

  // O = P V
  v4f oa[4] = {};
#pragma unroll
  for (int kk = 0; kk < 2; ++kk) {
    v8bf ap = *(const v8bf*)&sP[(w * 16 + la) * 72 + kk * 32 + lb * 8];
#pragma unroll
    for (int n = 0; n < 4; ++n) {
      const int vidx = (n * 16 + la) * 68 + kk * 32 + lb * 8;
      v4bf lo = *(const v4bf*)&sVt[vidx];
      v4bf hi = *(const v4bf*)&sVt[vidx + 4];
      v8bf bv;
#pragma unroll
      for (int i = 0; i < 4; ++i) { bv[i] = lo[i]; bv[i + 4] = hi[i]; }
      oa[n] = __builtin_amdgcn_mfma_f32_16x16x32_bf16(ap, bv, oa[n], 0, 0, 0);
    }
  }
#pragma unroll
  for (int j = 0; j < 4; ++j) {
    const float inv = 1.0f / sj[j];
#pragma unroll
    for (int n = 0; n < 4; ++n)
      O[(m0 + w * 16 + lb * 4 + j) * 512 + head * 64 + n * 16 + la] = f2bf(oa[n][j] * inv);
  }
}

// ---------------------------------------------------------------------------
extern "C" void kernel_launch(void* const* d_in, const int* in_sizes, int n_in,
                              void* d_out, int out_size, void* d_ws, size_t ws_size,
                              hipStream_t stream) {
  const float* hidden = (const float*)d_in[1];
  const float* qkv_w  = (const float*)d_in[2];
  const float* qkv_b  = (const float*)d_in[3];
  const float* proj_w = (const float*)d_in[4];
  const float* proj_b = (const float*)d_in[5];
  float* out = (float*)d_out;

  char* ws = (char*)d_ws;
  unsigned short* QKV = (unsigned short*)(ws);                    // 201,326,592 B
  unsigned short* Xg  = (unsigned short*)(ws + 201326592);        //  67,108,864 B (reused as O)
  unsigned short* Wq  = (unsigned short*)(ws + 268435456);        //   1,572,864 B
  unsigned short* Wp  = (unsigned short*)(ws + 270008320);        //     524,288 B
  if (ws_size < 270532608) return;  // workspace too small: fail loudly
  unsigned short* Obuf = Xg;        // Xg dead after GEMM1 -> alias

  k_transpose_cast<<<dim3(8, 24), 256, 0, stream>>>(qkv_w, Wq, 512, 1536);
  k_transpose_cast<<<dim3(8, 8),  256, 0, stream>>>(proj_w, Wp, 512, 512);
  k_gather_cast<<<16384, 256, 0, stream>>>(hidden, Xg);
  k_gemm_qkv<<<6144, 256, 0, stream>>>(Xg, Wq, qkv_b, QKV);
  k_attn<<<8192, 256, 0, stream>>>(QKV, Obuf);
  k_gemm_proj<<<2048, 256, 0, stream>>>(Obuf, Wp, proj_b, out);
}